// Round 3
// baseline (293.520 us; speedup 1.0000x reference)
//
#include <hip/hip_runtime.h>
#include <hip/hip_bf16.h>

// MKGCN fused kernel. Inputs: float32 + int32 (per reference); output: float32.
// B=8192, DIM=32, K=16 neighbors, 2 hops, 60 relations.
// Simplifications vs reference:
//  - attention scores = dot(user_emb, relation_emb[r]) -> precompute sdot[60]/block
//  - iteration-1 hop-0 attention == iteration-0 hop-0 attention (same rel rows, same user_emb)
// One block per batch element; 256 threads; everything staged through LDS.

#define DIMV 32
#define KN   16
#define NREL 60
#define NT   256

__device__ __forceinline__ float sigmoidf_(float x) { return 1.0f / (1.0f + __expf(-x)); }

__global__ __launch_bounds__(NT) void mkgcn_fused(
    const int* __restrict__ users,
    const int* __restrict__ items,
    const float* __restrict__ E,     // [1e6, 32]
    const float* __restrict__ R,     // [60, 32]
    const int* __restrict__ adjE,    // [1e6, 16]
    const int* __restrict__ adjR,    // [1e6, 16]
    const int* __restrict__ uhist,   // [1e5, 16]
    const float* __restrict__ Wg,    // [32, 32]
    const float* __restrict__ bg,    // [32]
    float* __restrict__ out)         // [B] float32
{
    const int b = blockIdx.x;
    const int t = threadIdx.x;

    __shared__ float ue[DIMV];          // user embedding
    __shared__ float sdot[NREL];        // dot(ue, relation_emb[r]) for all 60 relations
    __shared__ int   e1[KN];            // hop-1 entity ids
    __shared__ int   r1[KN];
    __shared__ int   e2off[256];        // hop-2 entity ids * DIMV (element offsets)
    __shared__ int   r2[256];
    __shared__ float v1[KN][DIMV];      // hop-1 entity vectors
    __shared__ float attn2[256];        // hop-1-node attention over hop-2 neighbors
    __shared__ float attn0[KN];         // item-node attention over hop-1 neighbors
    __shared__ float x1[KN][DIMV];      // (self + agg) for hop-1 nodes
    __shared__ float hv1[KN][DIMV];     // updated hop-1 vectors (after sigmoid)
    __shared__ float Wl[DIMV][DIMV];
    __shared__ float bl[DIMV];
    __shared__ float part[8][DIMV];     // user-history partial sums
    __shared__ int   hrow[KN];
    __shared__ float v0[DIMV];          // item vector
    __shared__ float x0[DIMV];
    __shared__ float h0[DIMV];

    const int user = users[b];
    const int item = items[b];

    // ---- phase 0: index rows + W/b/v0 ----
    if (t < KN) {
        hrow[t] = uhist[(long)user * KN + t];
    } else if (t < 2 * KN) {
        e1[t - KN] = adjE[(long)item * KN + (t - KN)];
    } else if (t < 3 * KN) {
        r1[t - 2 * KN] = adjR[(long)item * KN + (t - 2 * KN)];
    } else if (t >= 64 && t < 96) {
        v0[t - 64] = E[(long)item * DIMV + (t - 64)];
        bl[t - 64] = bg[t - 64];
    }
    {
        float* wflat = &Wl[0][0];
        #pragma unroll
        for (int i = t; i < DIMV * DIMV; i += NT) wflat[i] = Wg[i];
    }
    __syncthreads();

    // ---- phase 1: history gather partials, hop-2 adjacency, v1 ----
    {
        const int r = t >> 5, d = t & 31;
        part[r][d] = E[(long)hrow[r] * DIMV + d] + E[(long)hrow[r + 8] * DIMV + d];
    }
    {
        const int n = t >> 4, k = t & 15;
        const long base = (long)e1[n] * KN + k;
        e2off[t] = adjE[base] * DIMV;
        r2[t]    = adjR[base];
    }
    #pragma unroll
    for (int i = t; i < KN * DIMV; i += NT) {
        const int row = i >> 5, d = i & 31;
        v1[row][d] = E[(long)e1[row] * DIMV + d];
    }
    __syncthreads();

    // ---- phase 2: user embedding (mean over 16 history rows) ----
    if (t < DIMV) {
        float s = 0.f;
        #pragma unroll
        for (int r = 0; r < 8; r++) s += part[r][t];
        ue[t] = s * (1.0f / 16.0f);
    }
    __syncthreads();

    // ---- phase 3: sdot[r] = dot(ue, R[r]) for all 60 relations ----
    if (t < NREL) {
        const float* rr = R + t * DIMV;
        float s = 0.f;
        #pragma unroll
        for (int d = 0; d < DIMV; d++) s += ue[d] * rr[d];
        sdot[t] = s;
    }
    __syncthreads();

    // ---- phase 4: attention (softmax over 16-lane segments) ----
    {
        float s = sdot[r2[t]];
        float m = s;
        #pragma unroll
        for (int off = 1; off < 16; off <<= 1) m = fmaxf(m, __shfl_xor(m, off, 16));
        float e = __expf(s - m);
        float sum = e;
        #pragma unroll
        for (int off = 1; off < 16; off <<= 1) sum += __shfl_xor(sum, off, 16);
        attn2[t] = e / sum;
    }
    if (t < KN) {
        float s = sdot[r1[t]];
        float m = s;
        #pragma unroll
        for (int off = 1; off < 16; off <<= 1) m = fmaxf(m, __shfl_xor(m, off, 16));
        float e = __expf(s - m);
        float sum = e;
        #pragma unroll
        for (int off = 1; off < 16; off <<= 1) sum += __shfl_xor(sum, off, 16);
        attn0[t] = e / sum;
    }
    __syncthreads();

    // ---- phase 5: hop-1 node aggregation over hop-2 neighbors (the hot gather) ----
    #pragma unroll
    for (int p = 0; p < 2; p++) {
        const int n = (t >> 5) + 8 * p;
        const int d = t & 31;
        const int base = n * KN;
        float acc = 0.f;
        #pragma unroll
        for (int k = 0; k < KN; k++) {
            acc += attn2[base + k] * E[(long)e2off[base + k] + d];
        }
        x1[n][d] = v1[n][d] + acc;
    }
    __syncthreads();

    // ---- phase 6: hop-1 matvec (x1 @ W + b), sigmoid ----
    #pragma unroll
    for (int p = 0; p < 2; p++) {
        const int n = (t >> 5) + 8 * p;
        const int dp = t & 31;
        float acc = bl[dp];
        #pragma unroll
        for (int d = 0; d < DIMV; d++) acc += x1[n][d] * Wl[d][dp];
        hv1[n][dp] = sigmoidf_(acc);
    }
    __syncthreads();

    // ---- phase 7: item-node aggregation over original hop-1 vectors ----
    if (t < DIMV) {
        float a = 0.f;
        #pragma unroll
        for (int k = 0; k < KN; k++) a += attn0[k] * v1[k][t];
        x0[t] = v0[t] + a;
    }
    __syncthreads();

    // ---- phase 8: item matvec, sigmoid ----
    if (t < DIMV) {
        float acc = bl[t];
        #pragma unroll
        for (int d = 0; d < DIMV; d++) acc += x0[d] * Wl[d][t];
        h0[t] = sigmoidf_(acc);
    }
    __syncthreads();

    // ---- phase 9: iteration-1 aggregation (same attn0) over updated hop-1 vectors ----
    if (t < DIMV) {
        float a = 0.f;
        #pragma unroll
        for (int k = 0; k < KN; k++) a += attn0[k] * hv1[k][t];
        x0[t] = h0[t] + a;
    }
    __syncthreads();

    // ---- phase 10: final matvec + tanh, dot with ue, sigmoid ----
    if (t < DIMV) {
        float acc = bl[t];
        #pragma unroll
        for (int d = 0; d < DIMV; d++) acc += x0[d] * Wl[d][t];
        const float ie = tanhf(acc);
        float p = ue[t] * ie;
        #pragma unroll
        for (int off = 1; off < 32; off <<= 1) p += __shfl_xor(p, off, 32);
        if (t == 0) out[b] = sigmoidf_(p);
    }
}

extern "C" void kernel_launch(void* const* d_in, const int* in_sizes, int n_in,
                              void* d_out, int out_size, void* d_ws, size_t ws_size,
                              hipStream_t stream) {
    const int* users   = (const int*)d_in[0];
    const int* items   = (const int*)d_in[1];
    const float* E     = (const float*)d_in[2];
    const float* R     = (const float*)d_in[3];
    const int* adjE    = (const int*)d_in[4];
    const int* adjR    = (const int*)d_in[5];
    const int* uhist   = (const int*)d_in[6];
    const float* Wg    = (const float*)d_in[7];
    const float* bg    = (const float*)d_in[8];
    float* out         = (float*)d_out;

    const int B = in_sizes[0];
    mkgcn_fused<<<B, NT, 0, stream>>>(users, items, E, R, adjE, adjR, uhist, Wg, bg, out);
}